// Round 1
// baseline (1088.995 us; speedup 1.0000x reference)
//
#include <hip/hip_runtime.h>
#include <cstdint>
#include <cstddef>

// ---------------------------------------------------------------------------
// EncoderBlock: S=4096, E=2048, H=8192, fp32 in/out, bf16 MFMA internally.
// GEMM structure = m97 ladder step 3: 128x128 tile, BK=32, 4 waves x 4x4
// mfma_f32_16x16x32_bf16, global_load_lds width=16 staging, 2-barrier K-loop.
// All GEMMs are C = A @ B^T with A[M,K], Bt[N,K] both K-contiguous.
// ---------------------------------------------------------------------------

constexpr int S = 4096;
constexpr int E = 2048;
constexpr int H = 8192;

typedef __bf16 bf16;
typedef bf16  bf16x8 __attribute__((ext_vector_type(8)));
typedef bf16  bf16x4 __attribute__((ext_vector_type(4)));
typedef float f32x4  __attribute__((ext_vector_type(4)));

typedef __attribute__((address_space(1))) void as1_void;
typedef __attribute__((address_space(3))) void as3_void;

__device__ __forceinline__ void ldg2lds16(const void* g, void* l) {
  // async global->LDS, 16B per lane; LDS dest must be wave-uniform base + lane*16
  __builtin_amdgcn_global_load_lds((as1_void*)g, (as3_void*)l, 16, 0, 0);
}

// ---------------------------------------------------------------------------
// GEMM: C[M,N] = A[M,K] @ Bt[N,K]^T, epilogue selected at compile time.
// EPI 0: out bf16 = acc + bias[col]
// EPI 1: out bf16 = acc + bias[row]            (V^T path)
// EPI 2: out bf16 = acc * scale                (scores)
// EPI 3: out f32  = acc + add[idx], + fused sum/sumsq atomics (attn residual)
// EPI 4: out bf16 = relu(acc + bias[col])      (FFN act)
// EPI 5: out f32  = acc + bias[col] + add[idx], + fused sum/sumsq (FFN residual)
// ---------------------------------------------------------------------------
template <int EPI>
__global__ __launch_bounds__(256)
void gemm_bt(const bf16* __restrict__ A, const bf16* __restrict__ Bt,
             bf16* __restrict__ Cb, float* __restrict__ Cf,
             const float* __restrict__ bias, const float* __restrict__ add,
             float* __restrict__ red, int M, int N, int K, float scale)
{
  __shared__ bf16 sA[128 * 32];
  __shared__ bf16 sB[128 * 32];

  const int tid  = threadIdx.x;
  const int lane = tid & 63;
  const int wave = tid >> 6;
  const int m0 = blockIdx.y * 128;
  const int n0 = blockIdx.x * 128;
  const int wm = (wave & 1) * 64;   // wave's m-offset within tile
  const int wn = (wave >> 1) * 64;  // wave's n-offset within tile

  // staging: thread t covers tile row (t>>2) (+64 for 2nd issue), 16B chunk (t&3)
  const int sr = tid >> 2;
  const int sc = (tid & 3) * 8;
  const bf16* gA  = A  + (size_t)(m0 + sr) * K + sc;
  const bf16* gA2 = gA + (size_t)64 * K;
  const bf16* gB  = Bt + (size_t)(n0 + sr) * K + sc;
  const bf16* gB2 = gB + (size_t)64 * K;
  bf16* lA  = &sA[tid * 8];          // == sr*32 + sc
  bf16* lA2 = lA + 64 * 32;
  bf16* lB  = &sB[tid * 8];
  bf16* lB2 = lB + 64 * 32;

  // MFMA fragment addressing: A[m=lane&15][k=(lane>>4)*8 + j]
  const int fr = lane & 15;
  const int fq = lane >> 4;
  const bf16* rA = &sA[(wm + fr) * 32 + fq * 8];
  const bf16* rB = &sB[(wn + fr) * 32 + fq * 8];

  f32x4 acc[4][4] = {};

  for (int k0 = 0; k0 < K; k0 += 32) {
    ldg2lds16(gA, lA);
    ldg2lds16(gA2, lA2);
    ldg2lds16(gB, lB);
    ldg2lds16(gB2, lB2);
    gA += 32; gA2 += 32; gB += 32; gB2 += 32;
    __syncthreads();   // drains vmcnt(0): staged tiles visible

    bf16x8 a[4], b[4];
#pragma unroll
    for (int i = 0; i < 4; ++i) a[i] = *(const bf16x8*)(rA + i * 16 * 32);
#pragma unroll
    for (int j = 0; j < 4; ++j) b[j] = *(const bf16x8*)(rB + j * 16 * 32);
#pragma unroll
    for (int i = 0; i < 4; ++i)
#pragma unroll
      for (int j = 0; j < 4; ++j)
        acc[i][j] = __builtin_amdgcn_mfma_f32_16x16x32_bf16(a[i], b[j], acc[i][j], 0, 0, 0);
    __syncthreads();   // reads done before next iteration overwrites LDS
  }

  // epilogue: C/D layout (16x16x32): row = (lane>>4)*4 + reg, col = lane&15
  const int er = m0 + wm + fq * 4;
  const int ec = n0 + wn + fr;
  float ls = 0.f, ls2 = 0.f;
#pragma unroll
  for (int i = 0; i < 4; ++i) {
#pragma unroll
    for (int r = 0; r < 4; ++r) {
      const int gr = er + i * 16 + r;
#pragma unroll
      for (int j = 0; j < 4; ++j) {
        const int gc = ec + j * 16;
        const size_t idx = (size_t)gr * N + gc;
        float v = acc[i][j][r];
        if (EPI == 0) {
          v += bias[gc];
          Cb[idx] = (bf16)v;
        } else if (EPI == 1) {
          v += bias[gr];
          Cb[idx] = (bf16)v;
        } else if (EPI == 2) {
          Cb[idx] = (bf16)(v * scale);
        } else if (EPI == 3) {
          v += add[idx];
          Cf[idx] = v; ls += v; ls2 += v * v;
        } else if (EPI == 4) {
          v += bias[gc];
          v = v > 0.f ? v : 0.f;
          Cb[idx] = (bf16)v;
        } else {  // EPI == 5
          v += bias[gc] + add[idx];
          Cf[idx] = v; ls += v; ls2 += v * v;
        }
      }
    }
  }

  if (EPI == 3 || EPI == 5) {
#pragma unroll
    for (int o = 32; o; o >>= 1) {
      ls  += __shfl_xor(ls,  o, 64);
      ls2 += __shfl_xor(ls2, o, 64);
    }
    float* sred = (float*)sA;  // safe: all waves past final barrier
    if (lane == 0) { sred[wave * 2] = ls; sred[wave * 2 + 1] = ls2; }
    __syncthreads();
    if (tid == 0) {
      atomicAdd(red,     sred[0] + sred[2] + sred[4] + sred[6]);
      atomicAdd(red + 1, sred[1] + sred[3] + sred[5] + sred[7]);
    }
  }
}

// ---------------------------------------------------------------------------
// fp32 -> bf16 elementwise (4/thread, exact-divisible grids only)
// ---------------------------------------------------------------------------
__global__ __launch_bounds__(256)
void cvt_f32_bf16(const float* __restrict__ src, bf16* __restrict__ dst)
{
  const size_t i = ((size_t)blockIdx.x * 256 + threadIdx.x) * 4;
  const float4 t = *(const float4*)(src + i);
  bf16x4 b;
  b[0] = (bf16)t.x; b[1] = (bf16)t.y; b[2] = (bf16)t.z; b[3] = (bf16)t.w;
  *(bf16x4*)(dst + i) = b;
}

// fp32 [R,C] -> bf16 [C,R] (tiled transpose+convert)
__global__ __launch_bounds__(256)
void transpose_cvt(const float* __restrict__ src, bf16* __restrict__ dst, int R, int C)
{
  __shared__ float tile[32][33];
  const int c0 = blockIdx.x * 32, r0 = blockIdx.y * 32;
  const int tx = threadIdx.x & 31, ty = threadIdx.x >> 5;
#pragma unroll
  for (int rr = ty; rr < 32; rr += 8)
    tile[rr][tx] = src[(size_t)(r0 + rr) * C + (c0 + tx)];
  __syncthreads();
#pragma unroll
  for (int rr = ty; rr < 32; rr += 8)
    dst[(size_t)(c0 + rr) * R + (r0 + tx)] = (bf16)tile[tx][rr];
}

// ---------------------------------------------------------------------------
// row softmax in place on bf16 [4096 x 4096]; one block per row
// ---------------------------------------------------------------------------
__global__ __launch_bounds__(256)
void softmax_rows(bf16* __restrict__ P)
{
  const int row  = blockIdx.x;
  bf16* p = P + (size_t)row * 4096;
  const int tid  = threadIdx.x;
  const int lane = tid & 63, wave = tid >> 6;

  bf16x8 c0 = *(const bf16x8*)(p + tid * 16);
  bf16x8 c1 = *(const bf16x8*)(p + tid * 16 + 8);
  float v[16];
#pragma unroll
  for (int i = 0; i < 8; ++i) { v[i] = (float)c0[i]; v[8 + i] = (float)c1[i]; }

  float m = v[0];
#pragma unroll
  for (int i = 1; i < 16; ++i) m = fmaxf(m, v[i]);
#pragma unroll
  for (int o = 32; o; o >>= 1) m = fmaxf(m, __shfl_xor(m, o, 64));
  __shared__ float sred[8];
  if (lane == 0) sred[wave] = m;
  __syncthreads();
  m = fmaxf(fmaxf(sred[0], sred[1]), fmaxf(sred[2], sred[3]));

  float s = 0.f;
#pragma unroll
  for (int i = 0; i < 16; ++i) { v[i] = __expf(v[i] - m); s += v[i]; }
#pragma unroll
  for (int o = 32; o; o >>= 1) s += __shfl_xor(s, o, 64);
  if (lane == 0) sred[4 + wave] = s;
  __syncthreads();
  s = sred[4] + sred[5] + sred[6] + sred[7];

  const float inv = 1.f / s;
  bf16x8 o0, o1;
#pragma unroll
  for (int i = 0; i < 8; ++i) { o0[i] = (bf16)(v[i] * inv); o1[i] = (bf16)(v[8 + i] * inv); }
  *(bf16x8*)(p + tid * 16)     = o0;
  *(bf16x8*)(p + tid * 16 + 8) = o1;
}

// ---------------------------------------------------------------------------
// global layernorm: finalize (mu, rsig) then apply
// ---------------------------------------------------------------------------
__global__ void ln_finalize(float* red, float n)
{
  const float mu  = red[0] / n;
  const float var = red[1] / n - mu * mu;
  red[2] = mu;
  red[3] = rsqrtf(var + 1e-5f);
}

__global__ __launch_bounds__(256)
void ln_apply(const float* __restrict__ y, const float* __restrict__ red,
              float* __restrict__ of, bf16* __restrict__ ob)
{
  const float mu = red[2], rs = red[3];
  const size_t i = ((size_t)blockIdx.x * 256 + threadIdx.x) * 4;
  float4 t = *(const float4*)(y + i);
  t.x = (t.x - mu) * rs; t.y = (t.y - mu) * rs;
  t.z = (t.z - mu) * rs; t.w = (t.w - mu) * rs;
  *(float4*)(of + i) = t;
  if (ob) {
    bf16x4 b;
    b[0] = (bf16)t.x; b[1] = (bf16)t.y; b[2] = (bf16)t.z; b[3] = (bf16)t.w;
    *(bf16x4*)(ob + i) = b;
  }
}

// ---------------------------------------------------------------------------
extern "C" void kernel_launch(void* const* d_in, const int* in_sizes, int n_in,
                              void* d_out, int out_size, void* d_ws, size_t ws_size,
                              hipStream_t stream)
{
  const float* x  = (const float*)d_in[0];
  const float* Wq = (const float*)d_in[1];
  const float* bq = (const float*)d_in[2];
  const float* Wk = (const float*)d_in[3];
  const float* bk = (const float*)d_in[4];
  const float* Wv = (const float*)d_in[5];
  const float* bv = (const float*)d_in[6];
  const float* W1 = (const float*)d_in[7];
  const float* b1 = (const float*)d_in[8];
  const float* W2 = (const float*)d_in[9];
  const float* b2 = (const float*)d_in[10];
  float* out = (float*)d_out;

  const size_t SE2 = (size_t)S * E * 2;   // 16 MB
  const size_t EE2 = (size_t)E * E * 2;   //  8 MB
  const size_t EH2 = (size_t)E * H * 2;   // 32 MB
  const size_t SE4 = (size_t)S * E * 4;   // 32 MB
  const size_t SH2 = (size_t)S * H * 2;   // 64 MB

  char* ws = (char*)d_ws;
  size_t off = 0;
  auto take = [&](size_t b) { char* p = ws + off; off += b; return p; };

  bf16* xb  = (bf16*)take(SE2);   // reused as hb after LN1 (xb dead by then)
  bf16* WqT = (bf16*)take(EE2);
  bf16* WkT = (bf16*)take(EE2);
  bf16* WvT = (bf16*)take(EE2);
  bf16* W1T = (bf16*)take(EH2);
  bf16* W2T = (bf16*)take(EH2);
  char* reg = take(SH2);          // Qb|Kb|Pb (16+16+32 MB) reused as act (64 MB)
  bf16* Qb  = (bf16*)reg;
  bf16* Kb  = (bf16*)(reg + SE2);
  bf16* Pb  = (bf16*)(reg + 2 * SE2);
  bf16* act = (bf16*)reg;
  bf16* VbT = (bf16*)take(SE2);
  float* y  = (float*)take(SE4);  // x+attn, then reused as h+ffn
  float* h  = (float*)take(SE4);
  float* red = (float*)take(256);
  bf16* hb = xb;

  hipMemsetAsync(red, 0, 32, stream);

  const dim3 blk(256);
  const int nElemBlocks = (S * E) / 1024;  // 4 elems/thread, 256 threads

  // bf16 conversions / weight transposes
  cvt_f32_bf16<<<dim3(nElemBlocks), blk, 0, stream>>>(x, xb);
  transpose_cvt<<<dim3(E / 32, E / 32), blk, 0, stream>>>(Wq, WqT, E, E);
  transpose_cvt<<<dim3(E / 32, E / 32), blk, 0, stream>>>(Wk, WkT, E, E);
  transpose_cvt<<<dim3(E / 32, E / 32), blk, 0, stream>>>(Wv, WvT, E, E);
  transpose_cvt<<<dim3(H / 32, E / 32), blk, 0, stream>>>(W1, W1T, E, H);
  transpose_cvt<<<dim3(E / 32, H / 32), blk, 0, stream>>>(W2, W2T, H, E);

  // projections: Q = x@Wq + bq, K = x@Wk + bk (bf16 out)
  gemm_bt<0><<<dim3(E / 128, S / 128), blk, 0, stream>>>(xb, WqT, Qb, nullptr, bq, nullptr, nullptr, S, E, E, 0.f);
  gemm_bt<0><<<dim3(E / 128, S / 128), blk, 0, stream>>>(xb, WkT, Kb, nullptr, bk, nullptr, nullptr, S, E, E, 0.f);
  // V^T[E,S] = WvT @ x^T + bv (per-row bias)
  gemm_bt<1><<<dim3(S / 128, E / 128), blk, 0, stream>>>(WvT, xb, VbT, nullptr, bv, nullptr, nullptr, E, S, E, 0.f);
  // scores = (Q @ K^T) / sqrt(S) -> bf16, softmax rows in place
  gemm_bt<2><<<dim3(S / 128, S / 128), blk, 0, stream>>>(Qb, Kb, Pb, nullptr, nullptr, nullptr, nullptr, S, S, E, 1.0f / 64.0f);
  softmax_rows<<<dim3(S), blk, 0, stream>>>(Pb);
  // y = x + P @ V (fp32, fused LN1 partial sums)
  gemm_bt<3><<<dim3(E / 128, S / 128), blk, 0, stream>>>(Pb, VbT, nullptr, y, nullptr, x, red, S, E, S, 0.f);
  ln_finalize<<<1, 1, 0, stream>>>(red, (float)((size_t)S * E));
  ln_apply<<<dim3(nElemBlocks), blk, 0, stream>>>(y, red, h, hb);
  // act = relu(h @ W1 + b1) -> bf16
  gemm_bt<4><<<dim3(H / 128, S / 128), blk, 0, stream>>>(hb, W1T, act, nullptr, b1, nullptr, nullptr, S, H, E, 0.f);
  // y2 = h + act @ W2 + b2 (fp32, fused LN2 partial sums)
  gemm_bt<5><<<dim3(E / 128, S / 128), blk, 0, stream>>>(act, W2T, nullptr, y, b2, h, red + 4, S, E, H, 0.f);
  ln_finalize<<<1, 1, 0, stream>>>(red + 4, (float)((size_t)S * E));
  ln_apply<<<dim3(nElemBlocks), blk, 0, stream>>>(y, red + 4, out, nullptr);
}